// Round 8
// baseline (413.190 us; speedup 1.0000x reference)
//
#include <hip/hip_runtime.h>
#include <hip/hip_bf16.h>
#include <math.h>

// ---------------------------------------------------------------------------
// Qwen3 attention block: T=4096, HIDDEN=2048, 16 Q heads, 8 KV heads,
// HEAD_DIM=128, rope theta 1e6, rms eps 1e-6, causal.
// fp32 in/out; bf16 internally for MFMA with fp32 accumulation.
// ---------------------------------------------------------------------------

typedef __bf16 bf16;
typedef __bf16 bf16x4 __attribute__((ext_vector_type(4)));
typedef __bf16 bf16x8 __attribute__((ext_vector_type(8)));
typedef float  f32x4  __attribute__((ext_vector_type(4)));

__device__ __forceinline__ f32x4 mfma16(bf16x8 a, bf16x8 b, f32x4 c) {
  return __builtin_amdgcn_mfma_f32_16x16x32_bf16(a, b, c, 0, 0, 0);
}

// 4 chained 16x16x16 bf16 MFMAs accumulating into one C/D quad.
__device__ __forceinline__ void mfma16x16_chain4(const bf16x4& a0, const bf16x4& a1,
                                                 const bf16x4& a2, const bf16x4& a3,
                                                 const bf16x4& b0, const bf16x4& b1,
                                                 const bf16x4& b2, const bf16x4& b3,
                                                 f32x4& c) {
  asm volatile(
      "s_nop 2\n\t"
      "v_mfma_f32_16x16x16_bf16 %0, %1, %5, %0\n\t"
      "v_mfma_f32_16x16x16_bf16 %0, %2, %6, %0\n\t"
      "v_mfma_f32_16x16x16_bf16 %0, %3, %7, %0\n\t"
      "v_mfma_f32_16x16x16_bf16 %0, %4, %8, %0"
      : "+v"(c)
      : "v"(a0), "v"(a1), "v"(a2), "v"(a3),
        "v"(b0), "v"(b1), "v"(b2), "v"(b3));
}

// Async global->LDS DMA, 16B per lane. LDS dest is wave-uniform base +
// lane*16 (hardware rule); global src is per-lane.
__device__ __forceinline__ void gload_lds16(const bf16* g, bf16* l) {
  __builtin_amdgcn_global_load_lds(
      (const __attribute__((address_space(1))) unsigned int*)g,
      (__attribute__((address_space(3))) unsigned int*)l, 16, 0, 0);
}

__device__ __forceinline__ void store_c(float* p, float v) { *p = v; }
__device__ __forceinline__ void store_c(bf16* p, float v) { *p = (bf16)v; }

// ---------------------------------------------------------------------------
// fp32 -> bf16 cast, 8 elems/thread
// ---------------------------------------------------------------------------
__global__ __launch_bounds__(256) void cast_bf16(const float* __restrict__ s,
                                                 bf16* __restrict__ d) {
  int i = blockIdx.x * 256 + threadIdx.x;
  float4 a = reinterpret_cast<const float4*>(s)[i * 2];
  float4 b = reinterpret_cast<const float4*>(s)[i * 2 + 1];
  bf16x8 v = {(bf16)a.x, (bf16)a.y, (bf16)a.z, (bf16)a.w,
              (bf16)b.x, (bf16)b.y, (bf16)b.z, (bf16)b.w};
  reinterpret_cast<bf16x8*>(d)[i] = v;
}

// ---------------------------------------------------------------------------
// gemm8ph v2: C[M][N] = A[M][K] @ B[N][K]^T, bf16 out. True m201-style
// quadrant-phased 8-phase schedule. 256^2 tile, BK=64, 512 threads.
//
// R6's version phased over fm (every half-tile live every phase -> forced
// vmcnt(0) drain per K-tile, 1-tile pipeline, 763 TF). v2 phases over
// C-QUADRANTS: all 8 waves (4x2 grid, 32x64 each) cooperate on one 128x128
// quadrant per phase, so each phase touches ONE A-half + ONE B-half:
//   p0:(A0,B0)  p1:(A0,B1)  p2:(A1,B0)  p3:(A1,B1)
// Die-times: A0 dead after p1, B0 after p2, B1/A1 after p3. Staging rolls
// one half-tile (2 gloads) per phase into the slot that just died:
//   p0: B1(t+1)  p1: A1(t+1)  p2: A0(t+2)  p3: B0(t+2)
// Single counted wait per K-tile at p3: vmcnt(4) == "everything staged
// <= p1(t) has landed" -> tile t+1's halves (staged p2(t-1),p3(t-1),
// p0(t),p1(t)) are ALL guaranteed, while A0/B0(t+2) (4 loads) stay in
// flight across the barrier -- never drained to 0 in the main loop (T4).
// Slot-reuse race-freedom: each restage targets a slot whose last ds_read
// completed before the previous phase's trailing barrier (lgkmcnt(0) is
// emitted before the MFMAs that consume the reads, which precede it).
// Prologue: tile0 (8 loads) + A0(1)+B0(1) (4) -> vmcnt(4). Tail: vmcnt(0)
// at t=NT-2, no wait at NT-1.
// T2 swizzle: 16B-chunk c' = c ^ (row&7), pre-swizzled global source
// (rule #21), read koff = ((ks*4+quad) ^ (l16&7))*8. T1 XCD swizzle.
// sched_barrier(0) after every s_barrier pins ds_reads/stages in-phase.
// ---------------------------------------------------------------------------
__global__ __launch_bounds__(512, 2) void gemm8ph(const bf16* __restrict__ A,
                                                  const bf16* __restrict__ B,
                                                  bf16* __restrict__ C,
                                                  int M, int N, int K) {
  __shared__ __align__(16) bf16 As[2][256 * 64];
  __shared__ __align__(16) bf16 Bs[2][256 * 64];

  const int tid  = threadIdx.x;
  const int lane = tid & 63, wid = tid >> 6;
  const int quad = lane >> 4, l16 = lane & 15;
  const int wq_r = wid >> 1, wq_c = wid & 1;  // 4x2 wave grid per quadrant

  // XCD-aware bijective swizzle (nwg multiple of 8)
  const int nbx = N >> 8;
  const int nwg = (M >> 8) * nbx;
  const int cpx = nwg >> 3;
  const int swz = ((int)blockIdx.x & 7) * cpx + ((int)blockIdx.x >> 3);
  const int m0 = (swz / nbx) << 8;
  const int n0 = (swz % nbx) << 8;

  // staging: gload g covers rows g*64 + tid/8, LDS elems g*4096 + tid*8.
  // Source col chunk pre-swizzled: (tid&7)^(row&7).
  const int srow = tid >> 3;
  const int scol = (((tid & 7) ^ (srow & 7)) << 3);
  const bf16* aS = &A[(size_t)(m0 + srow) * K + scol];
  const bf16* bS = &B[(size_t)(n0 + srow) * K + scol];
  const size_t rk64 = (size_t)64 * K;

  // read-side swizzled k-offsets within a 64-elem row (row&7 == l16&7)
  const int koff0 = ((quad)     ^ (l16 & 7)) << 3;
  const int koff1 = ((4 + quad) ^ (l16 & 7)) << 3;

  const f32x4 zero = {0.f, 0.f, 0.f, 0.f};
  f32x4 acc[2][2][2][4];  // [qm][qn][fm][fn]
#pragma unroll
  for (int a = 0; a < 2; ++a)
#pragma unroll
    for (int b = 0; b < 2; ++b)
#pragma unroll
      for (int c = 0; c < 2; ++c)
#pragma unroll
        for (int d = 0; d < 4; ++d) acc[a][b][c][d] = zero;

  const int NT = K >> 6;

  // stage half h (0: rows 0-127, 1: rows 128-255) of tile tt into buffer bb
#define STAGE_A(bb, h, tt) do {                                              \
    const size_t kk = (size_t)(tt) * 64;                                     \
    gload_lds16(aS + (size_t)(2*(h))   * rk64 + kk, &As[bb][(2*(h))*4096   + tid*8]); \
    gload_lds16(aS + (size_t)(2*(h)+1) * rk64 + kk, &As[bb][(2*(h)+1)*4096 + tid*8]); \
  } while (0)
#define STAGE_B(bb, h, tt) do {                                              \
    const size_t kk = (size_t)(tt) * 64;                                     \
    gload_lds16(bS + (size_t)(2*(h))   * rk64 + kk, &Bs[bb][(2*(h))*4096   + tid*8]); \
    gload_lds16(bS + (size_t)(2*(h)+1) * rk64 + kk, &Bs[bb][(2*(h)+1)*4096 + tid*8]); \
  } while (0)

  // prologue: tile 0 complete + A0(1), B0(1); leave the latter in flight
  STAGE_A(0, 0, 0); STAGE_B(0, 0, 0); STAGE_B(0, 1, 0); STAGE_A(0, 1, 0);
  STAGE_A(1, 0, 1); STAGE_B(1, 0, 1);
  asm volatile("s_waitcnt vmcnt(4)" ::: "memory");
  __builtin_amdgcn_s_barrier();
  __builtin_amdgcn_sched_barrier(0);

  for (int t = 0; t < NT; ++t) {
    const int cb = t & 1;
    const bf16* AsL = As[cb];
    const bf16* BsL = Bs[cb];
    const bool s1 = (t + 1 < NT);   // stage tile t+1 halves (B1, A1)
    const bool s2 = (t + 2 < NT);   // stage tile t+2 halves (A0, B0)

#pragma unroll
    for (int p = 0; p < 4; ++p) {
      const int qm = p >> 1, qn = p & 1;

      // ---- ds_read this quadrant's fragments (4 A + 8 B x b128) ----
      const bf16* aB = &AsL[(qm * 128 + wq_r * 32 + l16) * 64];
      const bf16* bB = &BsL[(qn * 128 + wq_c * 64 + l16) * 64];
      bf16x8 a0k0 = *reinterpret_cast<const bf16x8*>(&aB[koff0]);
      bf16x8 a0k1 = *reinterpret_cast<const bf16x8*>(&aB[koff1]);
      bf16x8 a1k0 = *reinterpret_cast<const bf16x8*>(&aB[16 * 64 + koff0]);
      bf16x8 a1k1 = *reinterpret_cast<const bf16x8*>(&aB[16 * 64 + koff1]);
      bf16x8 bf_[4][2];
#pragma unroll
      for (int fn = 0; fn < 4; ++fn) {
        bf_[fn][0] = *reinterpret_cast<const bf16x8*>(&bB[fn * 16 * 64 + koff0]);
        bf_[fn][1] = *reinterpret_cast<const bf16x8*>(&bB[fn * 16 * 64 + koff1]);
      }

      // ---- stage one half-tile into the slot that just died ----
      if (p == 0 && s1) STAGE_B(cb ^ 1, 1, t + 1);  // B1(t+1)
      if (p == 1 && s1) STAGE_A(cb ^ 1, 1, t + 1);  // A1(t+1)
      if (p == 2 && s2) STAGE_A(cb,     0, t + 2);  // A0(t+2) (A0(t) dead p1)
      if (p == 3 && s2) STAGE_B(cb,     0, t + 2);  // B0(t+2) (B0(t) dead p2)

      __builtin_amdgcn_s_barrier();
      __builtin_amdgcn_sched_barrier(0);

      __builtin_amdgcn_s_setprio(1);
#pragma unroll
      for (int fn = 0; fn < 4; ++fn) {
        acc[qm][qn][0][fn] = mfma16(a0k1, bf_[fn][1],
                                    mfma16(a0k0, bf_[fn][0], acc[qm][qn][0][fn]));
        acc[qm][qn][1][fn] = mfma16(a1k1, bf_[fn][1],
                                    mfma16(a1k0, bf_[fn][0], acc[qm][qn][1][fn]));
      }
      __builtin_amdgcn_s_setprio(0);

      if (p == 3) {
        if (s2)      asm volatile("s_waitcnt vmcnt(4)" ::: "memory");
        else if (s1) asm volatile("s_waitcnt vmcnt(0)" ::: "memory");
      }
      __builtin_amdgcn_s_barrier();
      __builtin_amdgcn_sched_barrier(0);
    }
  }
#undef STAGE_A
#undef STAGE_B

#pragma unroll
  for (int qm = 0; qm < 2; ++qm)
#pragma unroll
    for (int qn = 0; qn < 2; ++qn)
#pragma unroll
      for (int fm = 0; fm < 2; ++fm)
#pragma unroll
        for (int fn = 0; fn < 4; ++fn)
#pragma unroll
          for (int r = 0; r < 4; ++r) {
            int row = m0 + qm * 128 + wq_r * 32 + fm * 16 + quad * 4 + r;
            int col = n0 + qn * 128 + wq_c * 64 + fn * 16 + l16;
            C[(size_t)row * N + col] = (bf16)acc[qm][qn][fm][fn][r];
          }
}

// ---------------------------------------------------------------------------
// gemm_bt v3 (R2-verified): 128x128 tile, BK=32, 2-phase double-buffer,
// global_load_lds staging. Kept for gemm2 (N=2048 -> 512 blocks = 2/CU).
// ---------------------------------------------------------------------------
__device__ __forceinline__ void gemm_step(const bf16* AsL, const bf16* BsL,
                                          int wm, int wn, int l16, int quad,
                                          f32x4 (&acc)[4][4]) {
  bf16x8 af[4], bfr[4];
#pragma unroll
  for (int i = 0; i < 4; ++i)
    af[i] = *reinterpret_cast<const bf16x8*>(&AsL[(wm + i * 16 + l16) * 32 + quad * 8]);
#pragma unroll
  for (int j = 0; j < 4; ++j)
    bfr[j] = *reinterpret_cast<const bf16x8*>(&BsL[(wn + j * 16 + l16) * 32 + quad * 8]);
#pragma unroll
  for (int i = 0; i < 4; ++i)
#pragma unroll
    for (int j = 0; j < 4; ++j)
      acc[i][j] = mfma16(af[i], bfr[j], acc[i][j]);
}

template <typename TC>
__global__ __launch_bounds__(256, 4) void gemm_bt(const bf16* __restrict__ A,
                                                  const bf16* __restrict__ B,
                                                  TC* __restrict__ C,
                                                  int M, int N, int K) {
  __shared__ __align__(16) bf16 As[2][128 * 32];
  __shared__ __align__(16) bf16 Bs[2][128 * 32];

  const int tid  = threadIdx.x;
  const int wave = tid >> 6, lane = tid & 63;
  const int quad = lane >> 4, l16 = lane & 15;
  const int wm = (wave >> 1) * 64, wn = (wave & 1) * 64;
  const int n0 = blockIdx.x * 128, m0 = blockIdx.y * 128;

  const int r0 = tid >> 2;
  const int c0 = (tid & 3) * 8;
  const size_t aBase = (size_t)(m0 + r0) * K + c0;
  const size_t bBase = (size_t)(n0 + r0) * K + c0;
  const size_t rowK64 = (size_t)64 * K;

  const f32x4 zero = {0.f, 0.f, 0.f, 0.f};
  f32x4 acc[4][4];
#pragma unroll
  for (int i = 0; i < 4; ++i)
#pragma unroll
    for (int j = 0; j < 4; ++j) acc[i][j] = zero;

  gload_lds16(&A[aBase],          &As[0][tid * 8]);
  gload_lds16(&A[aBase + rowK64], &As[0][2048 + tid * 8]);
  gload_lds16(&B[bBase],          &Bs[0][tid * 8]);
  gload_lds16(&B[bBase + rowK64], &Bs[0][2048 + tid * 8]);
  __syncthreads();

  int cur = 0;
  for (int k0 = 32; k0 < K; k0 += 32) {
    const int nb = cur ^ 1;
    gload_lds16(&A[aBase + k0],          &As[nb][tid * 8]);
    gload_lds16(&A[aBase + rowK64 + k0], &As[nb][2048 + tid * 8]);
    gload_lds16(&B[bBase + k0],          &Bs[nb][tid * 8]);
    gload_lds16(&B[bBase + rowK64 + k0], &Bs[nb][2048 + tid * 8]);

    gemm_step(As[cur], Bs[cur], wm, wn, l16, quad, acc);

    __syncthreads();
    cur = nb;
  }
  gemm_step(As[cur], Bs[cur], wm, wn, l16, quad, acc);

#pragma unroll
  for (int i = 0; i < 4; ++i)
#pragma unroll
    for (int j = 0; j < 4; ++j)
#pragma unroll
      for (int r = 0; r < 4; ++r) {
        int row = m0 + wm + i * 16 + quad * 4 + r;
        int col = n0 + wn + j * 16 + l16;
        store_c(&C[(size_t)row * N + col], acc[i][j][r]);
      }
}

// ---------------------------------------------------------------------------
// norm_rope v2 (R3-verified) — unchanged
// ---------------------------------------------------------------------------
__global__ __launch_bounds__(256) void norm_rope(const bf16* __restrict__ qkv,
                                                 const float* __restrict__ qw,
                                                 const float* __restrict__ kw,
                                                 const int* __restrict__ pos,
                                                 bf16* __restrict__ qn,
                                                 bf16* __restrict__ kn) {
  const int t = blockIdx.x;
  const int wv = threadIdx.x >> 6, l = threadIdx.x & 63;

  float inv = exp2f((float)l * (-19.93156856932417f / 64.0f));
  float fr = (float)pos[t] * inv;
  float sn, cs;
  sincosf(fr, &sn, &cs);
  const float qw1 = qw[l], qw2 = qw[l + 64];
  const float kw1 = kw[l], kw2 = kw[l + 64];
  const size_t rowb = (size_t)t * 4096;

#pragma unroll
  for (int i = 0; i < 6; ++i) {
    const int h = wv * 6 + i;            // 0..23, uniform per wave
    const bool isq = h < 16;
    const int col = isq ? h * 128 : 2048 + (h - 16) * 128;
    float x1 = (float)qkv[rowb + col + l];
    float x2 = (float)qkv[rowb + col + l + 64];
    float ss = x1 * x1 + x2 * x2;
#pragma unroll
    for (int o = 32; o >= 1; o >>= 1) ss += __shfl_xor(ss, o);
    float rms = rsqrtf(ss * (1.0f / 128.0f) + 1e-6f);
    float w1 = isq ? qw1 : kw1, w2 = isq ? qw2 : kw2;
    float xn1 = x1 * rms * w1, xn2 = x2 * rms * w2;
    float o1 = xn1 * cs - xn2 * sn;
    float o2 = xn2 * cs + xn1 * sn;
    if (isq) {
      qn[(size_t)t * 2048 + h * 128 + l] = (bf16)o1;
      qn[(size_t)t * 2048 + h * 128 + l + 64] = (bf16)o2;
    } else {
      kn[(size_t)t * 1024 + (h - 16) * 128 + l] = (bf16)o1;
      kn[(size_t)t * 1024 + (h - 16) * 128 + l + 64] = (bf16)o2;
    }
  }
}

// ---------------------------------------------------------------------------
// One-time V transpose — unchanged
// ---------------------------------------------------------------------------
__global__ __launch_bounds__(256) void transpose_v(const bf16* __restrict__ qkv,
                                                   bf16* __restrict__ vt) {
  __shared__ __align__(16) bf16 tile[128 * 72];
  const int t0 = blockIdx.x * 64, kvh = blockIdx.y;
  const int tid = threadIdx.x;
#pragma unroll
  for (int it = 0; it < 2; ++it) {
    int linear = it * 4096 + tid * 16;
    int r = linear >> 7, c = linear & 127;
    union { uint4 v; bf16 e[8]; } u0, u1;
    u0.v = *reinterpret_cast<const uint4*>(
        &qkv[(size_t)(t0 + r) * 4096 + 3072 + kvh * 128 + c]);
    u1.v = *reinterpret_cast<const uint4*>(
        &qkv[(size_t)(t0 + r) * 4096 + 3072 + kvh * 128 + c + 8]);
#pragma unroll
    for (int j = 0; j < 8; ++j) tile[(c + j) * 72 + r] = u0.e[j];
#pragma unroll
    for (int j = 0; j < 8; ++j) tile[(c + 8 + j) * 72 + r] = u1.e[j];
  }
  __syncthreads();
#pragma unroll
  for (int it = 0; it < 4; ++it) {
    int linear = it * 2048 + tid * 8;
    int d = linear >> 6, c = linear & 63;
    uint4 v = *reinterpret_cast<const uint4*>(&tile[d * 72 + c]);
    *reinterpret_cast<uint4*>(&vt[(size_t)(kvh * 128 + d) * 4096 + t0 + c]) = v;
  }
}

// ---------------------------------------------------------------------------
// Flash attention v8 (R3/R5-verified, 153 us) — unchanged
// ---------------------------------------------------------------------------
__global__ __launch_bounds__(256, 2) void attn(const bf16* __restrict__ q,
                                               const bf16* __restrict__ k,
                                               const bf16* __restrict__ vt,
                                               bf16* __restrict__ out) {
  __shared__ __align__(16) bf16 Ks[2][64 * 128];  // [buf][kv row][dim] swizzled
  __shared__ __align__(16) bf16 Vs[2][128 * 64];  // [buf][dim][kv row] swizzled

  const int head = blockIdx.y, kvh = head >> 1;
  const int bx = blockIdx.x;

  const int tid = threadIdx.x;
  const int wave = tid >> 6, lane = tid & 63;
  const int quad = lane >> 4, l16 = lane & 15;
  const float cExp = 0.08838834764831845f * 1.4426950408889634f; // scale*log2e
  const f32x4 zero = {0.f, 0.f, 0.f, 0.f};

  int kSrc[4], vSrc[4];
#pragma unroll
  for (int it = 0; it < 4; ++it) {
    int r = (wave * 4 + it) * 4 + (lane >> 4);
    kSrc[it] = r * 1024 + kvh * 128 + (((lane & 15) ^ (r & 7)) << 3);
    int d = (wave * 4 + it) * 8 + (lane >> 3);
    vSrc[it] = (kvh * 128 + d) * 4096 + (((lane & 7) ^ (lane >> 3)) << 3);
  }

  const int kswz = (l16 & 7) << 3;
  int koff[4], voff[4];
#pragma unroll
  for (int s = 0; s < 4; ++s) {
    koff[s] = (s * 32 + quad * 8) ^ kswz;
    voff[s] = (s * 16 + quad * 4) ^ kswz;
  }

#pragma unroll
  for (int it = 0; it < 4; ++it) {
    gload_lds16(&k[kSrc[it]], &Ks[0][(wave * 4 + it) * 512]);
    gload_lds16(&vt[vSrc[it]], &Vs[0][(wave * 4 + it) * 512]);
  }
  int cur = 0;

#pragma unroll
  for (int phase = 0; phase < 2; ++phase) {
    const int qt = phase == 0 ? bx : 63 - bx;
    const int q0 = qt * 64;
    const int kend = q0 + 64;
    const int qrow = q0 + wave * 16 + l16;

    bf16x8 qf[4];
#pragma unroll
    for (int s = 0; s < 4; ++s)
      qf[s] = *reinterpret_cast<const bf16x8*>(
          &q[(size_t)qrow * 2048 + head * 128 + s * 32 + quad * 8]);

    f32x4 o_acc[8];
#pragma unroll
    for (int dt = 0; dt < 8; ++dt) o_acc[dt] = zero;
    float m_i = -3.0e38f, l_i = 0.f;

    for (int k0 = 0; k0 < kend; k0 += 64) {
      __syncthreads();

      int nk0 = -1;
      if (k0 + 64 < kend)     nk0 = k0 + 64;
      else if (phase == 0)    nk0 = 0;
      if (nk0 >= 0) {
#pragma unroll
        for (int it = 0; it < 4; ++it) {
          gload_lds16(&k[kSrc[it] + nk0 * 1024],
                      &Ks[cur ^ 1][(wave * 4 + it) * 512]);
          gload_lds16(&vt[vSrc[it] + nk0],
                      &Vs[cur ^ 1][(wave * 4 + it) * 512]);
        }
      }

      const bf16* KsL = Ks[cur];
      const bf16* VsL = Vs[cur];

      f32x4 s_acc[4];
      __builtin_amdgcn_s_setprio(1);
#pragma unroll
      for (int mt = 0; mt < 4; ++mt) {
        bf16x8 kf[4];
#pragma unroll
        for (int ks = 0; ks < 4; ++ks)
          kf[ks] = *reinterpret_cast<const bf16x8*>(
              &KsL[(mt * 16 + l16) * 128 + koff[ks]]);
        f32x4 sa = zero;
#pragma unroll
        for (int ks = 0; ks < 4; ++ks) sa = mfma16(kf[ks], qf[ks], sa);
        s_acc[mt] = sa;
      }
      __builtin_amdgcn_s_setprio(0);

      if (k0 == q0) {
        int tq = wave * 16 + l16;
#pragma unroll
        for (int mt = 0; mt < 4; ++mt)
#pragma unroll
          for (int r = 0; r < 4; ++r) {
            int tk = mt * 16 + quad * 4 + r;
            if (tk > tq) s_acc[mt][r] = -3.0e38f;
          }
      }

      {
        float mx = -3.0e38f;
#pragma unroll
        for (int mt = 0; mt < 4; ++mt)
#pragma unroll
          for (int r = 0; r < 4; ++r) mx = fmaxf(mx, s_acc[mt][r]);
        mx = fmaxf(mx, __shfl_xor(mx, 16));
        mx = fmaxf(mx, __shfl_xor(mx, 32));
        if (!__all((mx - m_i) * cExp <= 8.0f)) {
          float mn = fmaxf(m_i, mx);
          float al = exp2f((m_i - mn) * cExp);
          m_i = mn;
          l_i *= al;
#pragma unroll
          for (int dt = 0; dt < 8; ++dt)
#pragma unroll
            for (int r = 0; r < 4; ++r) o_acc[dt][r] *= al;
        }
        float nmc = -m_i * cExp;
        float rs = 0.f;
#pragma unroll
        for (int mt = 0; mt < 4; ++mt)
#pragma unroll
          for (int r = 0; r < 4; ++r) {
            float pe = exp2f(fmaf(s_acc[mt][r], cExp, nmc));
            s_acc[mt][r] = pe;
            rs += pe;
          }
        rs += __shfl_xor(rs, 16);
        rs += __shfl_xor(rs, 32);
        l_i += rs;
      }

      bf16x4 pb[4];
#pragma unroll
      for (int mt = 0; mt < 4; ++mt) {
        bf16x4 t;
#pragma unroll
        for (int r = 0; r < 4; ++r) t[r] = (bf16)s_acc[mt][r];
        pb[mt] = t;
      }

      __builtin_amdgcn_s_setprio(1);
#pragma unroll
      for (int dt = 0; dt < 8; ++dt) {
        const bf16* vrow = &VsL[(dt * 16 + l16) * 64];
        bf16x4 va0 = *reinterpret_cast<const bf16x4*>(&vrow[voff[0]]);
        bf16x4 va1 = *reinterpret_cast<const bf16x4*>(&vrow[voff[1]]);
        bf16x4 va2 = *reinterpret_cast<const bf16x4*>(&vrow[voff[2]]);
        bf16x4 va3 = *reinterpret_cast<const bf16x4*>(&vrow[voff[3]]);
        mfma16x16_chain4(va0, va1, va2, va3, pb[0], pb[1], pb[2], pb[3],
                         o_acc[dt]);
      }
      __builtin_amdgcn_s_setprio(0);
      cur ^= 1;
    }

    float rl = __builtin_amdgcn_rcpf(l_i);
#pragma unroll
    for (int dt = 0; dt < 8; ++dt) {
      bf16x4 ov;
#pragma unroll
      for (int r = 0; r < 4; ++r) ov[r] = (bf16)(o_acc[dt][r] * rl);
      *reinterpret_cast<bf16x4*>(
          &out[(size_t)qrow * 2048 + head * 128 + dt * 16 + quad * 4]) = ov;
    }
  }
}

// ---------------------------------------------------------------------------
extern "C" void kernel_launch(void* const* d_in, const int* in_sizes, int n_in,
                              void* d_out, int out_size, void* d_ws, size_t ws_size,
                              hipStream_t stream) {
  const float* hidden = (const float*)d_in[0];
  const float* qkv_w  = (const float*)d_in[1];
  const float* qnw    = (const float*)d_in[2];
  const float* knw    = (const float*)d_in[3];
  const float* o_w    = (const float*)d_in[4];
  const int*   pos    = (const int*)d_in[5];

  bf16* qkv = (bf16*)d_ws;                       // 4096*4096
  bf16* qn  = qkv + (size_t)4096 * 4096;         // 4096*2048
  bf16* kn  = qn  + (size_t)4096 * 2048;         // 4096*1024
  bf16* vt  = kn  + (size_t)4096 * 1024;         // 1024*4096
  bf16* ao  = vt  + (size_t)1024 * 4096;         // 4096*2048
  bf16* hb  = ao;   // bf16 hidden, dead before attn writes ao
  bf16* wq  = kn;   // bf16 qkv_w, dead before norm_rope/transpose write kn/vt
  bf16* wo  = qn;   // bf16 o_w, cast after attn (qn dead)
  float* out = (float*)d_out;

  cast_bf16<<<4096, 256, 0, stream>>>(hidden, hb);
  cast_bf16<<<4096, 256, 0, stream>>>(qkv_w, wq);
  gemm8ph<<<256, 512, 0, stream>>>(hb, wq, qkv, 4096, 4096, 2048);
  norm_rope<<<4096, 256, 0, stream>>>(qkv, qnw, knw, pos, qn, kn);
  transpose_v<<<dim3(64, 8), 256, 0, stream>>>(qkv, vt);
  attn<<<dim3(32, 16), 256, 0, stream>>>(qn, kn, vt, ao);
  cast_bf16<<<2048, 256, 0, stream>>>(o_w, wo);
  gemm_bt<<<dim3(16, 32), 256, 0, stream>>>(ao, wo, out, 4096, 2048, 2048);
}

// Round 10
// 407.004 us; speedup vs baseline: 1.0152x; 1.0152x over previous
//
#include <hip/hip_runtime.h>
#include <hip/hip_bf16.h>
#include <math.h>

// ---------------------------------------------------------------------------
// Qwen3 attention block: T=4096, HIDDEN=2048, 16 Q heads, 8 KV heads,
// HEAD_DIM=128, rope theta 1e6, rms eps 1e-6, causal.
// fp32 in/out; bf16 internally for MFMA with fp32 accumulation.
// ---------------------------------------------------------------------------

typedef __bf16 bf16;
typedef __bf16 bf16x4 __attribute__((ext_vector_type(4)));
typedef __bf16 bf16x8 __attribute__((ext_vector_type(8)));
typedef float  f32x4  __attribute__((ext_vector_type(4)));

__device__ __forceinline__ f32x4 mfma16(bf16x8 a, bf16x8 b, f32x4 c) {
  return __builtin_amdgcn_mfma_f32_16x16x32_bf16(a, b, c, 0, 0, 0);
}

// 4 chained 16x16x16 bf16 MFMAs accumulating into one C/D quad.
__device__ __forceinline__ void mfma16x16_chain4(const bf16x4& a0, const bf16x4& a1,
                                                 const bf16x4& a2, const bf16x4& a3,
                                                 const bf16x4& b0, const bf16x4& b1,
                                                 const bf16x4& b2, const bf16x4& b3,
                                                 f32x4& c) {
  asm volatile(
      "s_nop 2\n\t"
      "v_mfma_f32_16x16x16_bf16 %0, %1, %5, %0\n\t"
      "v_mfma_f32_16x16x16_bf16 %0, %2, %6, %0\n\t"
      "v_mfma_f32_16x16x16_bf16 %0, %3, %7, %0\n\t"
      "v_mfma_f32_16x16x16_bf16 %0, %4, %8, %0"
      : "+v"(c)
      : "v"(a0), "v"(a1), "v"(a2), "v"(a3),
        "v"(b0), "v"(b1), "v"(b2), "v"(b3));
}

// Async global->LDS DMA, 16B per lane. LDS dest is wave-uniform base +
// lane*16 (hardware rule); global src is per-lane.
__device__ __forceinline__ void gload_lds16(const bf16* g, bf16* l) {
  __builtin_amdgcn_global_load_lds(
      (const __attribute__((address_space(1))) unsigned int*)g,
      (__attribute__((address_space(3))) unsigned int*)l, 16, 0, 0);
}

__device__ __forceinline__ void store_c(float* p, float v) { *p = v; }
__device__ __forceinline__ void store_c(bf16* p, float v) { *p = (bf16)v; }

// ---------------------------------------------------------------------------
// fp32 -> bf16 cast, 8 elems/thread
// ---------------------------------------------------------------------------
__global__ __launch_bounds__(256) void cast_bf16(const float* __restrict__ s,
                                                 bf16* __restrict__ d) {
  int i = blockIdx.x * 256 + threadIdx.x;
  float4 a = reinterpret_cast<const float4*>(s)[i * 2];
  float4 b = reinterpret_cast<const float4*>(s)[i * 2 + 1];
  bf16x8 v = {(bf16)a.x, (bf16)a.y, (bf16)a.z, (bf16)a.w,
              (bf16)b.x, (bf16)b.y, (bf16)b.z, (bf16)b.w};
  reinterpret_cast<bf16x8*>(d)[i] = v;
}

// ---------------------------------------------------------------------------
// gemm8ph v1 (R6-verified, total 399.1): 256^2 tile, BK=64, 512 threads,
// fm-phased 4-phase K-tile, double-buffered 2x64KB LDS, T2 swizzle,
// T1 XCD swizzle, setprio.
// ---------------------------------------------------------------------------
__global__ __launch_bounds__(512, 2) void gemm8ph(const bf16* __restrict__ A,
                                                  const bf16* __restrict__ B,
                                                  bf16* __restrict__ C,
                                                  int M, int N, int K) {
  __shared__ __align__(16) bf16 As[2][256 * 64];
  __shared__ __align__(16) bf16 Bs[2][256 * 64];

  const int tid  = threadIdx.x;
  const int lane = tid & 63, wid = tid >> 6;
  const int quad = lane >> 4, l16 = lane & 15;
  const int wr = wid >> 2, wc = wid & 3;  // 2 M-waves x 4 N-waves

  // XCD-aware bijective swizzle (nwg multiple of 8)
  const int nbx = N >> 8;
  const int nwg = (M >> 8) * nbx;
  const int cpx = nwg >> 3;
  const int swz = ((int)blockIdx.x & 7) * cpx + ((int)blockIdx.x >> 3);
  const int m0 = (swz / nbx) << 8;
  const int n0 = (swz % nbx) << 8;

  // staging: gload g covers rows g*64 + tid/8, LDS elems g*4096 + tid*8.
  // Source col chunk pre-swizzled: (tid&7)^(row&7).
  const int srow = tid >> 3;
  const int scol = (((tid & 7) ^ (srow & 7)) << 3);
  const bf16* aS = &A[(size_t)(m0 + srow) * K + scol];
  const bf16* bS = &B[(size_t)(n0 + srow) * K + scol];
  const size_t rk64 = (size_t)64 * K;

  // read-side swizzled k-offsets within a 64-elem row (row&7 == l16&7)
  const int koff0 = ((quad)     ^ (l16 & 7)) << 3;
  const int koff1 = ((4 + quad) ^ (l16 & 7)) << 3;

  const f32x4 zero = {0.f, 0.f, 0.f, 0.f};
  f32x4 acc[8][4];
#pragma unroll
  for (int i = 0; i < 8; ++i)
#pragma unroll
    for (int j = 0; j < 4; ++j) acc[i][j] = zero;

  const int NT = K >> 6;

  // prologue: stage tile 0 into buf 0
  {
    gload_lds16(aS,            &As[0][tid * 8]);
    gload_lds16(aS + rk64,     &As[0][4096 + tid * 8]);
    gload_lds16(aS + 2 * rk64, &As[0][8192 + tid * 8]);
    gload_lds16(aS + 3 * rk64, &As[0][12288 + tid * 8]);
    gload_lds16(bS,            &Bs[0][tid * 8]);
    gload_lds16(bS + rk64,     &Bs[0][4096 + tid * 8]);
    gload_lds16(bS + 2 * rk64, &Bs[0][8192 + tid * 8]);
    gload_lds16(bS + 3 * rk64, &Bs[0][12288 + tid * 8]);
  }
  asm volatile("s_waitcnt vmcnt(0)" ::: "memory");
  __builtin_amdgcn_s_barrier();

  for (int t = 0; t < NT; ++t) {
    const int c = t & 1;
    const bf16* AsL = As[c];
    const bf16* BsL = Bs[c];
    const bool pre = (t + 1 < NT);
    const size_t nk = (size_t)(t + 1) * 64;
    bf16* An = As[c ^ 1];
    bf16* Bn = Bs[c ^ 1];

    bf16x8 bfv[4][2];

#pragma unroll
    for (int p = 0; p < 4; ++p) {
      // ---- ds_read this phase's fragments ----
      if (p == 0) {
#pragma unroll
        for (int fn = 0; fn < 4; ++fn) {
          const bf16* bp = &BsL[(wc * 64 + fn * 16 + l16) * 64];
          bfv[fn][0] = *reinterpret_cast<const bf16x8*>(&bp[koff0]);
          bfv[fn][1] = *reinterpret_cast<const bf16x8*>(&bp[koff1]);
        }
      }
      const bf16* ap0 = &AsL[(wr * 128 + (2 * p) * 16 + l16) * 64];
      const bf16* ap1 = ap0 + 16 * 64;
      bf16x8 a0k0 = *reinterpret_cast<const bf16x8*>(&ap0[koff0]);
      bf16x8 a0k1 = *reinterpret_cast<const bf16x8*>(&ap0[koff1]);
      bf16x8 a1k0 = *reinterpret_cast<const bf16x8*>(&ap1[koff0]);
      bf16x8 a1k1 = *reinterpret_cast<const bf16x8*>(&ap1[koff1]);

      // ---- stage next tile: A-halves at p0, B-halves at p1 ----
      if (p == 0 && pre) {
        gload_lds16(aS + nk,            &An[tid * 8]);
        gload_lds16(aS + rk64 + nk,     &An[4096 + tid * 8]);
        gload_lds16(aS + 2 * rk64 + nk, &An[8192 + tid * 8]);
        gload_lds16(aS + 3 * rk64 + nk, &An[12288 + tid * 8]);
      }
      if (p == 1 && pre) {
        gload_lds16(bS + nk,            &Bn[tid * 8]);
        gload_lds16(bS + rk64 + nk,     &Bn[4096 + tid * 8]);
        gload_lds16(bS + 2 * rk64 + nk, &Bn[8192 + tid * 8]);
        gload_lds16(bS + 3 * rk64 + nk, &Bn[12288 + tid * 8]);
      }

      __builtin_amdgcn_s_barrier();
      __builtin_amdgcn_sched_barrier(0);

      __builtin_amdgcn_s_setprio(1);
#pragma unroll
      for (int fn = 0; fn < 4; ++fn) {
        acc[2 * p][fn]     = mfma16(a0k1, bfv[fn][1],
                                    mfma16(a0k0, bfv[fn][0], acc[2 * p][fn]));
        acc[2 * p + 1][fn] = mfma16(a1k1, bfv[fn][1],
                                    mfma16(a1k0, bfv[fn][0], acc[2 * p + 1][fn]));
      }
      __builtin_amdgcn_s_setprio(0);

      if (p == 3 && pre) {
        asm volatile("s_waitcnt vmcnt(0)" ::: "memory");
      }
      __builtin_amdgcn_s_barrier();
    }
  }

#pragma unroll
  for (int fm = 0; fm < 8; ++fm)
#pragma unroll
    for (int fn = 0; fn < 4; ++fn)
#pragma unroll
      for (int r = 0; r < 4; ++r) {
        int row = m0 + wr * 128 + fm * 16 + quad * 4 + r;
        int col = n0 + wc * 64 + fn * 16 + l16;
        C[(size_t)row * N + col] = (bf16)acc[fm][fn][r];
      }
}

// ---------------------------------------------------------------------------
// gemm_bt v3 (R2-verified): 128x128 tile, BK=32, 2-phase double-buffer,
// global_load_lds staging. Kept for gemm2 (N=2048 -> 512 blocks = 2/CU).
// ---------------------------------------------------------------------------
__device__ __forceinline__ void gemm_step(const bf16* AsL, const bf16* BsL,
                                          int wm, int wn, int l16, int quad,
                                          f32x4 (&acc)[4][4]) {
  bf16x8 af[4], bfr[4];
#pragma unroll
  for (int i = 0; i < 4; ++i)
    af[i] = *reinterpret_cast<const bf16x8*>(&AsL[(wm + i * 16 + l16) * 32 + quad * 8]);
#pragma unroll
  for (int j = 0; j < 4; ++j)
    bfr[j] = *reinterpret_cast<const bf16x8*>(&BsL[(wn + j * 16 + l16) * 32 + quad * 8]);
#pragma unroll
  for (int i = 0; i < 4; ++i)
#pragma unroll
    for (int j = 0; j < 4; ++j)
      acc[i][j] = mfma16(af[i], bfr[j], acc[i][j]);
}

template <typename TC>
__global__ __launch_bounds__(256, 4) void gemm_bt(const bf16* __restrict__ A,
                                                  const bf16* __restrict__ B,
                                                  TC* __restrict__ C,
                                                  int M, int N, int K) {
  __shared__ __align__(16) bf16 As[2][128 * 32];
  __shared__ __align__(16) bf16 Bs[2][128 * 32];

  const int tid  = threadIdx.x;
  const int wave = tid >> 6, lane = tid & 63;
  const int quad = lane >> 4, l16 = lane & 15;
  const int wm = (wave >> 1) * 64, wn = (wave & 1) * 64;
  const int n0 = blockIdx.x * 128, m0 = blockIdx.y * 128;

  const int r0 = tid >> 2;
  const int c0 = (tid & 3) * 8;
  const size_t aBase = (size_t)(m0 + r0) * K + c0;
  const size_t bBase = (size_t)(n0 + r0) * K + c0;
  const size_t rowK64 = (size_t)64 * K;

  const f32x4 zero = {0.f, 0.f, 0.f, 0.f};
  f32x4 acc[4][4];
#pragma unroll
  for (int i = 0; i < 4; ++i)
#pragma unroll
    for (int j = 0; j < 4; ++j) acc[i][j] = zero;

  gload_lds16(&A[aBase],          &As[0][tid * 8]);
  gload_lds16(&A[aBase + rowK64], &As[0][2048 + tid * 8]);
  gload_lds16(&B[bBase],          &Bs[0][tid * 8]);
  gload_lds16(&B[bBase + rowK64], &Bs[0][2048 + tid * 8]);
  __syncthreads();

  int cur = 0;
  for (int k0 = 32; k0 < K; k0 += 32) {
    const int nb = cur ^ 1;
    gload_lds16(&A[aBase + k0],          &As[nb][tid * 8]);
    gload_lds16(&A[aBase + rowK64 + k0], &As[nb][2048 + tid * 8]);
    gload_lds16(&B[bBase + k0],          &Bs[nb][tid * 8]);
    gload_lds16(&B[bBase + rowK64 + k0], &Bs[nb][2048 + tid * 8]);

    gemm_step(As[cur], Bs[cur], wm, wn, l16, quad, acc);

    __syncthreads();
    cur = nb;
  }
  gemm_step(As[cur], Bs[cur], wm, wn, l16, quad, acc);

#pragma unroll
  for (int i = 0; i < 4; ++i)
#pragma unroll
    for (int j = 0; j < 4; ++j)
#pragma unroll
      for (int r = 0; r < 4; ++r) {
        int row = m0 + wm + i * 16 + quad * 4 + r;
        int col = n0 + wn + j * 16 + l16;
        store_c(&C[(size_t)row * N + col], acc[i][j][r]);
      }
}

// ---------------------------------------------------------------------------
// norm_rope v2 (R3-verified) — unchanged
// ---------------------------------------------------------------------------
__global__ __launch_bounds__(256) void norm_rope(const bf16* __restrict__ qkv,
                                                 const float* __restrict__ qw,
                                                 const float* __restrict__ kw,
                                                 const int* __restrict__ pos,
                                                 bf16* __restrict__ qn,
                                                 bf16* __restrict__ kn) {
  const int t = blockIdx.x;
  const int wv = threadIdx.x >> 6, l = threadIdx.x & 63;

  float inv = exp2f((float)l * (-19.93156856932417f / 64.0f));
  float fr = (float)pos[t] * inv;
  float sn, cs;
  sincosf(fr, &sn, &cs);
  const float qw1 = qw[l], qw2 = qw[l + 64];
  const float kw1 = kw[l], kw2 = kw[l + 64];
  const size_t rowb = (size_t)t * 4096;

#pragma unroll
  for (int i = 0; i < 6; ++i) {
    const int h = wv * 6 + i;            // 0..23, uniform per wave
    const bool isq = h < 16;
    const int col = isq ? h * 128 : 2048 + (h - 16) * 128;
    float x1 = (float)qkv[rowb + col + l];
    float x2 = (float)qkv[rowb + col + l + 64];
    float ss = x1 * x1 + x2 * x2;
#pragma unroll
    for (int o = 32; o >= 1; o >>= 1) ss += __shfl_xor(ss, o);
    float rms = rsqrtf(ss * (1.0f / 128.0f) + 1e-6f);
    float w1 = isq ? qw1 : kw1, w2 = isq ? qw2 : kw2;
    float xn1 = x1 * rms * w1, xn2 = x2 * rms * w2;
    float o1 = xn1 * cs - xn2 * sn;
    float o2 = xn2 * cs + xn1 * sn;
    if (isq) {
      qn[(size_t)t * 2048 + h * 128 + l] = (bf16)o1;
      qn[(size_t)t * 2048 + h * 128 + l + 64] = (bf16)o2;
    } else {
      kn[(size_t)t * 1024 + (h - 16) * 128 + l] = (bf16)o1;
      kn[(size_t)t * 1024 + (h - 16) * 128 + l + 64] = (bf16)o2;
    }
  }
}

// ---------------------------------------------------------------------------
// One-time V transpose — unchanged
// ---------------------------------------------------------------------------
__global__ __launch_bounds__(256) void transpose_v(const bf16* __restrict__ qkv,
                                                   bf16* __restrict__ vt) {
  __shared__ __align__(16) bf16 tile[128 * 72];
  const int t0 = blockIdx.x * 64, kvh = blockIdx.y;
  const int tid = threadIdx.x;
#pragma unroll
  for (int it = 0; it < 2; ++it) {
    int linear = it * 4096 + tid * 16;
    int r = linear >> 7, c = linear & 127;
    union { uint4 v; bf16 e[8]; } u0, u1;
    u0.v = *reinterpret_cast<const uint4*>(
        &qkv[(size_t)(t0 + r) * 4096 + 3072 + kvh * 128 + c]);
    u1.v = *reinterpret_cast<const uint4*>(
        &qkv[(size_t)(t0 + r) * 4096 + 3072 + kvh * 128 + c + 8]);
#pragma unroll
    for (int j = 0; j < 8; ++j) tile[(c + j) * 72 + r] = u0.e[j];
#pragma unroll
    for (int j = 0; j < 8; ++j) tile[(c + 8 + j) * 72 + r] = u1.e[j];
  }
  __syncthreads();
#pragma unroll
  for (int it = 0; it < 4; ++it) {
    int linear = it * 2048 + tid * 8;
    int d = linear >> 6, c = linear & 63;
    uint4 v = *reinterpret_cast<const uint4*>(&tile[d * 72 + c]);
    *reinterpret_cast<uint4*>(&vt[(size_t)(kvh * 128 + d) * 4096 + t0 + c]) = v;
  }
}

// ---------------------------------------------------------------------------
// Flash attention v10 (resubmit of R8; bench infra failed, kernel audited
// sound): occupancy via 128-row q-tiles.
// v8 was latency-bound at 2 waves/SIMD: 2048 waves (512 blocks x 4) over
// 1024 SIMDs, LDS-capped at 2 blocks/CU. v10 doubles total waves to 4096:
// 512 blocks = 32 q-tiles (128 rows, 8 waves x 16 rows) x 16 heads, SAME
// 64KB double-buffered K/V LDS per block -> 2 blocks/CU x 8 waves =
// 4 waves/SIMD. v8 prefetch schedule kept byte-identical; K/V staged once
// per 128 q-rows (half the HBM fetch). Complement block mapping balances
// CU load. Causal mask on absolute indices. setprio (T5), defer-max (T13).
// ---------------------------------------------------------------------------
__global__ __launch_bounds__(512, 4) void attn(const bf16* __restrict__ q,
                                               const bf16* __restrict__ k,
                                               const bf16* __restrict__ vt,
                                               bf16* __restrict__ out) {
  __shared__ __align__(16) bf16 Ks[2][64 * 128];  // [buf][kv row][dim] swizzled
  __shared__ __align__(16) bf16 Vs[2][128 * 64];  // [buf][dim][kv row] swizzled

  const int bx   = blockIdx.x;        // 0..511
  const int slot = bx >> 4;           // 0..31
  const int head = bx & 15;
  const int kvh  = head >> 1;
  const int qt   = slot < 16 ? 31 - slot : slot - 16;  // complement pairing
  const int q0   = qt * 128;
  const int kend = q0 + 128;

  const int tid = threadIdx.x;
  const int wave = tid >> 6, lane = tid & 63;
  const int quad = lane >> 4, l16 = lane & 15;
  const float cExp = 0.08838834764831845f * 1.4426950408889634f; // scale*log2e
  const f32x4 zero = {0.f, 0.f, 0.f, 0.f};

  // staging source offsets (elements), pre-swizzled so the linear LDS
  // write lands in XOR-swizzled layout. Round it in {0,1}:
  //   K: row = it*32 + wave*4 + lane/16, chunk (lane&15)^(row&7)
  //   V: dim = it*64 + wave*8 + lane/8,  chunk (lane&7)^(dim&7)
  int kSrc[2], vSrc[2];
#pragma unroll
  for (int it = 0; it < 2; ++it) {
    int r = it * 32 + wave * 4 + (lane >> 4);
    kSrc[it] = r * 1024 + kvh * 128 + (((lane & 15) ^ (r & 7)) << 3);
    int d = it * 64 + wave * 8 + (lane >> 3);
    vSrc[it] = (kvh * 128 + d) * 4096 + (((lane & 7) ^ ((lane >> 3) & 7)) << 3);
  }
  // wave-uniform LDS dest bases: it*4096 + wave*512 (elems)

  // read-side swizzled offsets (row&7 == l16&7 for both K and V reads)
  const int kswz = (l16 & 7) << 3;
  int koff[4], voff[4];
#pragma unroll
  for (int s = 0; s < 4; ++s) {
    koff[s] = (s * 32 + quad * 8) ^ kswz;  // 16B-aligned within 128-elem row
    voff[s] = (s * 16 + quad * 4) ^ kswz;  // 8B-aligned within 64-elem row
  }

  // prologue: stage tile 0 into buffer 0 (async)
#pragma unroll
  for (int it = 0; it < 2; ++it) {
    gload_lds16(&k[kSrc[it]], &Ks[0][it * 4096 + wave * 512]);
    gload_lds16(&vt[vSrc[it]], &Vs[0][it * 4096 + wave * 512]);
  }
  int cur = 0;

  const int qrow = q0 + wave * 16 + l16;

  // Q fragments: B[n=l16][k=s*32+quad*8+j]
  bf16x8 qf[4];
#pragma unroll
  for (int s = 0; s < 4; ++s)
    qf[s] = *reinterpret_cast<const bf16x8*>(
        &q[(size_t)qrow * 2048 + head * 128 + s * 32 + quad * 8]);

  f32x4 o_acc[8];  // O^T: d = dt*16+quad*4+r, q = l16
#pragma unroll
  for (int dt = 0; dt < 8; ++dt) o_acc[dt] = zero;
  float m_i = -3.0e38f, l_i = 0.f;

  for (int k0 = 0; k0 < kend; k0 += 64) {
    // buf[cur]'s DMA (issued last iter / prologue) is drained by the
    // vmcnt(0) the compiler emits before s_barrier; all waves are also
    // done reading buf[cur^1], so it is free to restage.
    __syncthreads();

    // issue async DMA for next tile; stays in flight across this compute
    if (k0 + 64 < kend) {
#pragma unroll
      for (int it = 0; it < 2; ++it) {
        gload_lds16(&k[kSrc[it] + (k0 + 64) * 1024],
                    &Ks[cur ^ 1][it * 4096 + wave * 512]);
        gload_lds16(&vt[vSrc[it] + (k0 + 64)],
                    &Vs[cur ^ 1][it * 4096 + wave * 512]);
      }
    }

    const bf16* KsL = Ks[cur];
    const bf16* VsL = Vs[cur];

    // ---- S^T = K Q^T : rows t (4 tiles of 16), cols q (16) ----
    f32x4 s_acc[4];
    __builtin_amdgcn_s_setprio(1);
#pragma unroll
    for (int mt = 0; mt < 4; ++mt) {
      bf16x8 kf[4];
#pragma unroll
      for (int ks = 0; ks < 4; ++ks)
        kf[ks] = *reinterpret_cast<const bf16x8*>(
            &KsL[(mt * 16 + l16) * 128 + koff[ks]]);
      f32x4 sa = zero;
#pragma unroll
      for (int ks = 0; ks < 4; ++ks) sa = mfma16(kf[ks], qf[ks], sa);
      s_acc[mt] = sa;
    }
    __builtin_amdgcn_s_setprio(0);

    // ---- causal mask (any tile overlapping this wave's rows) ----
    if (k0 + 64 > q0 + wave * 16) {
      const int tq = qrow;  // absolute q index for this lane
#pragma unroll
      for (int mt = 0; mt < 4; ++mt)
#pragma unroll
        for (int r = 0; r < 4; ++r) {
          int tk = k0 + mt * 16 + quad * 4 + r;  // absolute kv index
          if (tk > tq) s_acc[mt][r] = -3.0e38f;
        }
    }

    // ---- online softmax with defer-max (T13) ----
    {
      float mx = -3.0e38f;
#pragma unroll
      for (int mt = 0; mt < 4; ++mt)
#pragma unroll
        for (int r = 0; r < 4; ++r) mx = fmaxf(mx, s_acc[mt][r]);
      mx = fmaxf(mx, __shfl_xor(mx, 16));
      mx = fmaxf(mx, __shfl_xor(mx, 32));
      if (!__all((mx - m_i) * cExp <= 8.0f)) {
        float mn = fmaxf(m_i, mx);
        float al = exp2f((m_i - mn) * cExp);
        m_i = mn;
        l_i *= al;
#pragma unroll
        for (int dt = 0; dt < 8; ++dt)
#pragma unroll
          for (int r = 0; r < 4; ++r) o_acc[dt][r] *= al;
      }
      float nmc = -m_i * cExp;
      float rs = 0.f;
#pragma unroll
      for (int mt = 0; mt < 4; ++mt)
#pragma unroll
        for (int r = 0; r < 4; ++r) {
          float pe = exp2f(fmaf(s_acc[mt][r], cExp, nmc));
          s_acc[mt][r] = pe;
          rs += pe;
        }
      rs += __shfl_xor(rs, 16);
      rs += __shfl_xor(rs, 32);
      l_i += rs;
    }

    // ---- pack P in-register: B[k=t=quad*4+j][n=q=l16] per mt ----
    bf16x4 pb[4];
#pragma unroll
    for (int mt = 0; mt < 4; ++mt) {
      bf16x4 t;
#pragma unroll
      for (int r = 0; r < 4; ++r) t[r] = (bf16)s_acc[mt][r];
      pb[mt] = t;
    }

    // ---- O^T += V^T P via chained 16x16x16 ----
    __builtin_amdgcn_s_setprio(1);
#pragma unroll
    for (int dt = 0; dt < 8; ++dt) {
      const bf16* vrow = &VsL[(dt * 16 + l16) * 64];
      bf16x4 va0 = *reinterpret_cast<const bf16x4*>(&vrow[voff[0]]);
      bf16x4 va1 = *reinterpret_cast<const bf16x4*>(&vrow[voff[1]]);
      bf16x4 va2 = *reinterpret_cast<const bf16x4*>(&vrow[voff[2]]);
      bf16x4 va3 = *reinterpret_cast<const bf16x4*>(&vrow[voff[3]]);
      mfma16x16_chain4(va0, va1, va2, va3, pb[0], pb[1], pb[2], pb[3],
                       o_acc[dt]);
    }
    __builtin_amdgcn_s_setprio(0);
    cur ^= 1;
  }

  // ---- epilogue: O = O^T/l, 4 contiguous d per reg-quad ----
  float rl = __builtin_amdgcn_rcpf(l_i);
#pragma unroll
  for (int dt = 0; dt < 8; ++dt) {
    bf16x4 ov;
#pragma unroll
    for (int r = 0; r < 4; ++r) ov[r] = (bf16)(o_acc[dt][r] * rl);
    *reinterpret_cast<bf16x4*>(
        &out[(size_t)qrow * 2048 + head * 128 + dt * 16 + quad * 4]) = ov;
  }
}

// ---------------------------------------------------------------------------
extern "C" void kernel_launch(void* const* d_in, const int* in_sizes, int n_in,
                              void* d_out, int out_size, void* d_ws, size_t ws_size,
                              hipStream_t stream) {
  const float* hidden = (const float*)d_in[0];
  const float* qkv_w  = (const float*)d_in[1];
  const float* qnw    = (const float*)d_in[2];
  const float* knw    = (const float*)d_in[3];
  const float* o_w    = (const float*)d_in[4];
  const int*   pos    = (const int*)d_in[5];

  bf16* qkv = (bf16*)d_ws;                       // 4096*4096
  bf16* qn  = qkv + (size_t)4096 * 4096;         // 4096*2048
  bf16* kn  = qn  + (size_t)4096 * 2048;         // 4096*1024
  bf16* vt  = kn  + (size_t)4096 * 1024;         // 1024*4096
  bf16* ao  = vt  + (size_t)1024 * 4096;         // 4096*2048
  bf16* hb  = ao;   // bf16 hidden, dead before attn writes ao
  bf16* wq  = kn;   // bf16 qkv_w, dead before norm_rope/transpose write kn/vt
  bf16* wo  = qn;   // bf16 o_w, cast after attn (qn dead)
  float* out = (float*)d_out;

  cast_bf16<<<4096, 256, 0, stream>>>(hidden, hb);
  cast_bf16<<<4096, 256, 0, stream>>>(qkv_w, wq);
  gemm8ph<<<256, 512, 0, stream>>>(hb, wq, qkv, 4096, 4096, 2048);
  norm_rope<<<4096, 256, 0, stream>>>(qkv, qnw, knw, pos, qn, kn);
  transpose_v<<<dim3(64, 8), 256, 0, stream>>>(qkv, vt);
  attn<<<512, 512, 0, stream>>>(qn, kn, vt, ao);
  cast_bf16<<<2048, 256, 0, stream>>>(o_w, wo);
  gemm_bt<<<dim3(16, 32), 256, 0, stream>>>(ao, wo, out, 4096, 2048, 2048);
}

// Round 11
// 402.023 us; speedup vs baseline: 1.0278x; 1.0124x over previous
//
#include <hip/hip_runtime.h>
#include <hip/hip_bf16.h>
#include <math.h>

// ---------------------------------------------------------------------------
// Qwen3 attention block: T=4096, HIDDEN=2048, 16 Q heads, 8 KV heads,
// HEAD_DIM=128, rope theta 1e6, rms eps 1e-6, causal.
// fp32 in/out; bf16 internally for MFMA with fp32 accumulation.
// ---------------------------------------------------------------------------

typedef __bf16 bf16;
typedef __bf16 bf16x4 __attribute__((ext_vector_type(4)));
typedef __bf16 bf16x8 __attribute__((ext_vector_type(8)));
typedef float  f32x4  __attribute__((ext_vector_type(4)));

__device__ __forceinline__ f32x4 mfma16(bf16x8 a, bf16x8 b, f32x4 c) {
  return __builtin_amdgcn_mfma_f32_16x16x32_bf16(a, b, c, 0, 0, 0);
}

// 4 chained 16x16x16 bf16 MFMAs accumulating into one C/D quad.
__device__ __forceinline__ void mfma16x16_chain4(const bf16x4& a0, const bf16x4& a1,
                                                 const bf16x4& a2, const bf16x4& a3,
                                                 const bf16x4& b0, const bf16x4& b1,
                                                 const bf16x4& b2, const bf16x4& b3,
                                                 f32x4& c) {
  asm volatile(
      "s_nop 2\n\t"
      "v_mfma_f32_16x16x16_bf16 %0, %1, %5, %0\n\t"
      "v_mfma_f32_16x16x16_bf16 %0, %2, %6, %0\n\t"
      "v_mfma_f32_16x16x16_bf16 %0, %3, %7, %0\n\t"
      "v_mfma_f32_16x16x16_bf16 %0, %4, %8, %0"
      : "+v"(c)
      : "v"(a0), "v"(a1), "v"(a2), "v"(a3),
        "v"(b0), "v"(b1), "v"(b2), "v"(b3));
}

// Async global->LDS DMA, 16B per lane. LDS dest is wave-uniform base +
// lane*16 (hardware rule); global src is per-lane.
__device__ __forceinline__ void gload_lds16(const bf16* g, bf16* l) {
  __builtin_amdgcn_global_load_lds(
      (const __attribute__((address_space(1))) unsigned int*)g,
      (__attribute__((address_space(3))) unsigned int*)l, 16, 0, 0);
}

__device__ __forceinline__ void store_c(float* p, float v) { *p = v; }
__device__ __forceinline__ void store_c(bf16* p, float v) { *p = (bf16)v; }

// ---------------------------------------------------------------------------
// fp32 -> bf16 cast, 8 elems/thread
// ---------------------------------------------------------------------------
__global__ __launch_bounds__(256) void cast_bf16(const float* __restrict__ s,
                                                 bf16* __restrict__ d) {
  int i = blockIdx.x * 256 + threadIdx.x;
  float4 a = reinterpret_cast<const float4*>(s)[i * 2];
  float4 b = reinterpret_cast<const float4*>(s)[i * 2 + 1];
  bf16x8 v = {(bf16)a.x, (bf16)a.y, (bf16)a.z, (bf16)a.w,
              (bf16)b.x, (bf16)b.y, (bf16)b.z, (bf16)b.w};
  reinterpret_cast<bf16x8*>(d)[i] = v;
}

// ---------------------------------------------------------------------------
// gemm8ph v1 (R6-verified): 256^2 tile, BK=64, 512 threads, fm-phased
// 4-phase K-tile, double-buffered 2x64KB LDS, T2 swizzle, T1 XCD swizzle,
// setprio. Used for gemm1 (4096x4096x2048, 256 blocks = 1/CU).
// ---------------------------------------------------------------------------
__global__ __launch_bounds__(512, 2) void gemm8ph(const bf16* __restrict__ A,
                                                  const bf16* __restrict__ B,
                                                  bf16* __restrict__ C,
                                                  int M, int N, int K) {
  __shared__ __align__(16) bf16 As[2][256 * 64];
  __shared__ __align__(16) bf16 Bs[2][256 * 64];

  const int tid  = threadIdx.x;
  const int lane = tid & 63, wid = tid >> 6;
  const int quad = lane >> 4, l16 = lane & 15;
  const int wr = wid >> 2, wc = wid & 3;  // 2 M-waves x 4 N-waves

  // XCD-aware bijective swizzle (nwg multiple of 8)
  const int nbx = N >> 8;
  const int nwg = (M >> 8) * nbx;
  const int cpx = nwg >> 3;
  const int swz = ((int)blockIdx.x & 7) * cpx + ((int)blockIdx.x >> 3);
  const int m0 = (swz / nbx) << 8;
  const int n0 = (swz % nbx) << 8;

  // staging: gload g covers rows g*64 + tid/8, LDS elems g*4096 + tid*8.
  // Source col chunk pre-swizzled: (tid&7)^(row&7).
  const int srow = tid >> 3;
  const int scol = (((tid & 7) ^ (srow & 7)) << 3);
  const bf16* aS = &A[(size_t)(m0 + srow) * K + scol];
  const bf16* bS = &B[(size_t)(n0 + srow) * K + scol];
  const size_t rk64 = (size_t)64 * K;

  // read-side swizzled k-offsets within a 64-elem row (row&7 == l16&7)
  const int koff0 = ((quad)     ^ (l16 & 7)) << 3;
  const int koff1 = ((4 + quad) ^ (l16 & 7)) << 3;

  const f32x4 zero = {0.f, 0.f, 0.f, 0.f};
  f32x4 acc[8][4];
#pragma unroll
  for (int i = 0; i < 8; ++i)
#pragma unroll
    for (int j = 0; j < 4; ++j) acc[i][j] = zero;

  const int NT = K >> 6;

  // prologue: stage tile 0 into buf 0
  {
    gload_lds16(aS,            &As[0][tid * 8]);
    gload_lds16(aS + rk64,     &As[0][4096 + tid * 8]);
    gload_lds16(aS + 2 * rk64, &As[0][8192 + tid * 8]);
    gload_lds16(aS + 3 * rk64, &As[0][12288 + tid * 8]);
    gload_lds16(bS,            &Bs[0][tid * 8]);
    gload_lds16(bS + rk64,     &Bs[0][4096 + tid * 8]);
    gload_lds16(bS + 2 * rk64, &Bs[0][8192 + tid * 8]);
    gload_lds16(bS + 3 * rk64, &Bs[0][12288 + tid * 8]);
  }
  asm volatile("s_waitcnt vmcnt(0)" ::: "memory");
  __builtin_amdgcn_s_barrier();

  for (int t = 0; t < NT; ++t) {
    const int c = t & 1;
    const bf16* AsL = As[c];
    const bf16* BsL = Bs[c];
    const bool pre = (t + 1 < NT);
    const size_t nk = (size_t)(t + 1) * 64;
    bf16* An = As[c ^ 1];
    bf16* Bn = Bs[c ^ 1];

    bf16x8 bfv[4][2];

#pragma unroll
    for (int p = 0; p < 4; ++p) {
      // ---- ds_read this phase's fragments ----
      if (p == 0) {
#pragma unroll
        for (int fn = 0; fn < 4; ++fn) {
          const bf16* bp = &BsL[(wc * 64 + fn * 16 + l16) * 64];
          bfv[fn][0] = *reinterpret_cast<const bf16x8*>(&bp[koff0]);
          bfv[fn][1] = *reinterpret_cast<const bf16x8*>(&bp[koff1]);
        }
      }
      const bf16* ap0 = &AsL[(wr * 128 + (2 * p) * 16 + l16) * 64];
      const bf16* ap1 = ap0 + 16 * 64;
      bf16x8 a0k0 = *reinterpret_cast<const bf16x8*>(&ap0[koff0]);
      bf16x8 a0k1 = *reinterpret_cast<const bf16x8*>(&ap0[koff1]);
      bf16x8 a1k0 = *reinterpret_cast<const bf16x8*>(&ap1[koff0]);
      bf16x8 a1k1 = *reinterpret_cast<const bf16x8*>(&ap1[koff1]);

      // ---- stage next tile: A-halves at p0, B-halves at p1 ----
      if (p == 0 && pre) {
        gload_lds16(aS + nk,            &An[tid * 8]);
        gload_lds16(aS + rk64 + nk,     &An[4096 + tid * 8]);
        gload_lds16(aS + 2 * rk64 + nk, &An[8192 + tid * 8]);
        gload_lds16(aS + 3 * rk64 + nk, &An[12288 + tid * 8]);
      }
      if (p == 1 && pre) {
        gload_lds16(bS + nk,            &Bn[tid * 8]);
        gload_lds16(bS + rk64 + nk,     &Bn[4096 + tid * 8]);
        gload_lds16(bS + 2 * rk64 + nk, &Bn[8192 + tid * 8]);
        gload_lds16(bS + 3 * rk64 + nk, &Bn[12288 + tid * 8]);
      }

      __builtin_amdgcn_s_barrier();
      __builtin_amdgcn_sched_barrier(0);

      __builtin_amdgcn_s_setprio(1);
#pragma unroll
      for (int fn = 0; fn < 4; ++fn) {
        acc[2 * p][fn]     = mfma16(a0k1, bfv[fn][1],
                                    mfma16(a0k0, bfv[fn][0], acc[2 * p][fn]));
        acc[2 * p + 1][fn] = mfma16(a1k1, bfv[fn][1],
                                    mfma16(a1k0, bfv[fn][0], acc[2 * p + 1][fn]));
      }
      __builtin_amdgcn_s_setprio(0);

      if (p == 3 && pre) {
        asm volatile("s_waitcnt vmcnt(0)" ::: "memory");
      }
      __builtin_amdgcn_s_barrier();
    }
  }

#pragma unroll
  for (int fm = 0; fm < 8; ++fm)
#pragma unroll
    for (int fn = 0; fn < 4; ++fn)
#pragma unroll
      for (int r = 0; r < 4; ++r) {
        int row = m0 + wr * 128 + fm * 16 + quad * 4 + r;
        int col = n0 + wc * 64 + fn * 16 + l16;
        C[(size_t)row * N + col] = (bf16)acc[fm][fn][r];
      }
}

// ---------------------------------------------------------------------------
// gemm8ph_n128: BN=128 parameterization of the R6-verified gemm8ph template
// for gemm2 (4096x2048x2048 -> grid 16x16 = 256 blocks = exactly 1/CU; a
// BN=256 grid would be 128 blocks = half the CUs idle). Same 4-phase
// schedule, staging discipline, T2 swizzle, vmcnt placement; only the
// B-tile shrinks (128x64 = 16KB/buffer, 2 staging gloads, per-wave fn=2,
// acc[8][2]). LDS 96KB. Parameter change inherits the template's
// verification (two-lane discipline); `passed` refchecks.
// ---------------------------------------------------------------------------
template <typename TC>
__global__ __launch_bounds__(512, 2) void gemm8ph_n128(const bf16* __restrict__ A,
                                                       const bf16* __restrict__ B,
                                                       TC* __restrict__ C,
                                                       int M, int N, int K) {
  __shared__ __align__(16) bf16 As[2][256 * 64];
  __shared__ __align__(16) bf16 Bs[2][128 * 64];

  const int tid  = threadIdx.x;
  const int lane = tid & 63, wid = tid >> 6;
  const int quad = lane >> 4, l16 = lane & 15;
  const int wr = wid >> 2, wc = wid & 3;  // 2 M-waves x 4 N-waves (32 cols each)

  // XCD-aware bijective swizzle (nwg = 256, multiple of 8)
  const int nbx = N >> 7;
  const int nwg = (M >> 8) * nbx;
  const int cpx = nwg >> 3;
  const int swz = ((int)blockIdx.x & 7) * cpx + ((int)blockIdx.x >> 3);
  const int m0 = (swz / nbx) << 8;
  const int n0 = (swz % nbx) << 7;

  const int srow = tid >> 3;
  const int scol = (((tid & 7) ^ (srow & 7)) << 3);
  const bf16* aS = &A[(size_t)(m0 + srow) * K + scol];
  const bf16* bS = &B[(size_t)(n0 + srow) * K + scol];
  const size_t rk64 = (size_t)64 * K;

  const int koff0 = ((quad)     ^ (l16 & 7)) << 3;
  const int koff1 = ((4 + quad) ^ (l16 & 7)) << 3;

  const f32x4 zero = {0.f, 0.f, 0.f, 0.f};
  f32x4 acc[8][2];
#pragma unroll
  for (int i = 0; i < 8; ++i)
#pragma unroll
    for (int j = 0; j < 2; ++j) acc[i][j] = zero;

  const int NT = K >> 6;

  // prologue: stage tile 0 into buf 0 (A: 4 gloads, B: 2 gloads)
  {
    gload_lds16(aS,            &As[0][tid * 8]);
    gload_lds16(aS + rk64,     &As[0][4096 + tid * 8]);
    gload_lds16(aS + 2 * rk64, &As[0][8192 + tid * 8]);
    gload_lds16(aS + 3 * rk64, &As[0][12288 + tid * 8]);
    gload_lds16(bS,            &Bs[0][tid * 8]);
    gload_lds16(bS + rk64,     &Bs[0][4096 + tid * 8]);
  }
  asm volatile("s_waitcnt vmcnt(0)" ::: "memory");
  __builtin_amdgcn_s_barrier();

  for (int t = 0; t < NT; ++t) {
    const int c = t & 1;
    const bf16* AsL = As[c];
    const bf16* BsL = Bs[c];
    const bool pre = (t + 1 < NT);
    const size_t nk = (size_t)(t + 1) * 64;
    bf16* An = As[c ^ 1];
    bf16* Bn = Bs[c ^ 1];

    bf16x8 bfv[2][2];

#pragma unroll
    for (int p = 0; p < 4; ++p) {
      if (p == 0) {
#pragma unroll
        for (int fn = 0; fn < 2; ++fn) {
          const bf16* bp = &BsL[(wc * 32 + fn * 16 + l16) * 64];
          bfv[fn][0] = *reinterpret_cast<const bf16x8*>(&bp[koff0]);
          bfv[fn][1] = *reinterpret_cast<const bf16x8*>(&bp[koff1]);
        }
      }
      const bf16* ap0 = &AsL[(wr * 128 + (2 * p) * 16 + l16) * 64];
      const bf16* ap1 = ap0 + 16 * 64;
      bf16x8 a0k0 = *reinterpret_cast<const bf16x8*>(&ap0[koff0]);
      bf16x8 a0k1 = *reinterpret_cast<const bf16x8*>(&ap0[koff1]);
      bf16x8 a1k0 = *reinterpret_cast<const bf16x8*>(&ap1[koff0]);
      bf16x8 a1k1 = *reinterpret_cast<const bf16x8*>(&ap1[koff1]);

      if (p == 0 && pre) {
        gload_lds16(aS + nk,            &An[tid * 8]);
        gload_lds16(aS + rk64 + nk,     &An[4096 + tid * 8]);
        gload_lds16(aS + 2 * rk64 + nk, &An[8192 + tid * 8]);
        gload_lds16(aS + 3 * rk64 + nk, &An[12288 + tid * 8]);
      }
      if (p == 1 && pre) {
        gload_lds16(bS + nk,        &Bn[tid * 8]);
        gload_lds16(bS + rk64 + nk, &Bn[4096 + tid * 8]);
      }

      __builtin_amdgcn_s_barrier();
      __builtin_amdgcn_sched_barrier(0);

      __builtin_amdgcn_s_setprio(1);
#pragma unroll
      for (int fn = 0; fn < 2; ++fn) {
        acc[2 * p][fn]     = mfma16(a0k1, bfv[fn][1],
                                    mfma16(a0k0, bfv[fn][0], acc[2 * p][fn]));
        acc[2 * p + 1][fn] = mfma16(a1k1, bfv[fn][1],
                                    mfma16(a1k0, bfv[fn][0], acc[2 * p + 1][fn]));
      }
      __builtin_amdgcn_s_setprio(0);

      if (p == 3 && pre) {
        asm volatile("s_waitcnt vmcnt(0)" ::: "memory");
      }
      __builtin_amdgcn_s_barrier();
    }
  }

#pragma unroll
  for (int fm = 0; fm < 8; ++fm)
#pragma unroll
    for (int fn = 0; fn < 2; ++fn)
#pragma unroll
      for (int r = 0; r < 4; ++r) {
        int row = m0 + wr * 128 + fm * 16 + quad * 4 + r;
        int col = n0 + wc * 32 + fn * 16 + l16;
        store_c(&C[(size_t)row * N + col], acc[fm][fn][r]);
      }
}

// ---------------------------------------------------------------------------
// gemm_bt v3 (R2-verified, retained as fallback; currently uninstantiated)
// ---------------------------------------------------------------------------
__device__ __forceinline__ void gemm_step(const bf16* AsL, const bf16* BsL,
                                          int wm, int wn, int l16, int quad,
                                          f32x4 (&acc)[4][4]) {
  bf16x8 af[4], bfr[4];
#pragma unroll
  for (int i = 0; i < 4; ++i)
    af[i] = *reinterpret_cast<const bf16x8*>(&AsL[(wm + i * 16 + l16) * 32 + quad * 8]);
#pragma unroll
  for (int j = 0; j < 4; ++j)
    bfr[j] = *reinterpret_cast<const bf16x8*>(&BsL[(wn + j * 16 + l16) * 32 + quad * 8]);
#pragma unroll
  for (int i = 0; i < 4; ++i)
#pragma unroll
    for (int j = 0; j < 4; ++j)
      acc[i][j] = mfma16(af[i], bfr[j], acc[i][j]);
}

template <typename TC>
__global__ __launch_bounds__(256, 4) void gemm_bt(const bf16* __restrict__ A,
                                                  const bf16* __restrict__ B,
                                                  TC* __restrict__ C,
                                                  int M, int N, int K) {
  __shared__ __align__(16) bf16 As[2][128 * 32];
  __shared__ __align__(16) bf16 Bs[2][128 * 32];

  const int tid  = threadIdx.x;
  const int wave = tid >> 6, lane = tid & 63;
  const int quad = lane >> 4, l16 = lane & 15;
  const int wm = (wave >> 1) * 64, wn = (wave & 1) * 64;
  const int n0 = blockIdx.x * 128, m0 = blockIdx.y * 128;

  const int r0 = tid >> 2;
  const int c0 = (tid & 3) * 8;
  const size_t aBase = (size_t)(m0 + r0) * K + c0;
  const size_t bBase = (size_t)(n0 + r0) * K + c0;
  const size_t rowK64 = (size_t)64 * K;

  const f32x4 zero = {0.f, 0.f, 0.f, 0.f};
  f32x4 acc[4][4];
#pragma unroll
  for (int i = 0; i < 4; ++i)
#pragma unroll
    for (int j = 0; j < 4; ++j) acc[i][j] = zero;

  gload_lds16(&A[aBase],          &As[0][tid * 8]);
  gload_lds16(&A[aBase + rowK64], &As[0][2048 + tid * 8]);
  gload_lds16(&B[bBase],          &Bs[0][tid * 8]);
  gload_lds16(&B[bBase + rowK64], &Bs[0][2048 + tid * 8]);
  __syncthreads();

  int cur = 0;
  for (int k0 = 32; k0 < K; k0 += 32) {
    const int nb = cur ^ 1;
    gload_lds16(&A[aBase + k0],          &As[nb][tid * 8]);
    gload_lds16(&A[aBase + rowK64 + k0], &As[nb][2048 + tid * 8]);
    gload_lds16(&B[bBase + k0],          &Bs[nb][tid * 8]);
    gload_lds16(&B[bBase + rowK64 + k0], &Bs[nb][2048 + tid * 8]);

    gemm_step(As[cur], Bs[cur], wm, wn, l16, quad, acc);

    __syncthreads();
    cur = nb;
  }
  gemm_step(As[cur], Bs[cur], wm, wn, l16, quad, acc);

#pragma unroll
  for (int i = 0; i < 4; ++i)
#pragma unroll
    for (int j = 0; j < 4; ++j)
#pragma unroll
      for (int r = 0; r < 4; ++r) {
        int row = m0 + wm + i * 16 + quad * 4 + r;
        int col = n0 + wn + j * 16 + l16;
        store_c(&C[(size_t)row * N + col], acc[i][j][r]);
      }
}

// ---------------------------------------------------------------------------
// norm_rope v2 (R3-verified) — unchanged
// ---------------------------------------------------------------------------
__global__ __launch_bounds__(256) void norm_rope(const bf16* __restrict__ qkv,
                                                 const float* __restrict__ qw,
                                                 const float* __restrict__ kw,
                                                 const int* __restrict__ pos,
                                                 bf16* __restrict__ qn,
                                                 bf16* __restrict__ kn) {
  const int t = blockIdx.x;
  const int wv = threadIdx.x >> 6, l = threadIdx.x & 63;

  float inv = exp2f((float)l * (-19.93156856932417f / 64.0f));
  float fr = (float)pos[t] * inv;
  float sn, cs;
  sincosf(fr, &sn, &cs);
  const float qw1 = qw[l], qw2 = qw[l + 64];
  const float kw1 = kw[l], kw2 = kw[l + 64];
  const size_t rowb = (size_t)t * 4096;

#pragma unroll
  for (int i = 0; i < 6; ++i) {
    const int h = wv * 6 + i;            // 0..23, uniform per wave
    const bool isq = h < 16;
    const int col = isq ? h * 128 : 2048 + (h - 16) * 128;
    float x1 = (float)qkv[rowb + col + l];
    float x2 = (float)qkv[rowb + col + l + 64];
    float ss = x1 * x1 + x2 * x2;
#pragma unroll
    for (int o = 32; o >= 1; o >>= 1) ss += __shfl_xor(ss, o);
    float rms = rsqrtf(ss * (1.0f / 128.0f) + 1e-6f);
    float w1 = isq ? qw1 : kw1, w2 = isq ? qw2 : kw2;
    float xn1 = x1 * rms * w1, xn2 = x2 * rms * w2;
    float o1 = xn1 * cs - xn2 * sn;
    float o2 = xn2 * cs + xn1 * sn;
    if (isq) {
      qn[(size_t)t * 2048 + h * 128 + l] = (bf16)o1;
      qn[(size_t)t * 2048 + h * 128 + l + 64] = (bf16)o2;
    } else {
      kn[(size_t)t * 1024 + (h - 16) * 128 + l] = (bf16)o1;
      kn[(size_t)t * 1024 + (h - 16) * 128 + l + 64] = (bf16)o2;
    }
  }
}

// ---------------------------------------------------------------------------
// One-time V transpose — unchanged
// ---------------------------------------------------------------------------
__global__ __launch_bounds__(256) void transpose_v(const bf16* __restrict__ qkv,
                                                   bf16* __restrict__ vt) {
  __shared__ __align__(16) bf16 tile[128 * 72];
  const int t0 = blockIdx.x * 64, kvh = blockIdx.y;
  const int tid = threadIdx.x;
#pragma unroll
  for (int it = 0; it < 2; ++it) {
    int linear = it * 4096 + tid * 16;
    int r = linear >> 7, c = linear & 127;
    union { uint4 v; bf16 e[8]; } u0, u1;
    u0.v = *reinterpret_cast<const uint4*>(
        &qkv[(size_t)(t0 + r) * 4096 + 3072 + kvh * 128 + c]);
    u1.v = *reinterpret_cast<const uint4*>(
        &qkv[(size_t)(t0 + r) * 4096 + 3072 + kvh * 128 + c + 8]);
#pragma unroll
    for (int j = 0; j < 8; ++j) tile[(c + j) * 72 + r] = u0.e[j];
#pragma unroll
    for (int j = 0; j < 8; ++j) tile[(c + 8 + j) * 72 + r] = u1.e[j];
  }
  __syncthreads();
#pragma unroll
  for (int it = 0; it < 4; ++it) {
    int linear = it * 2048 + tid * 8;
    int d = linear >> 6, c = linear & 63;
    uint4 v = *reinterpret_cast<const uint4*>(&tile[d * 72 + c]);
    *reinterpret_cast<uint4*>(&vt[(size_t)(kvh * 128 + d) * 4096 + t0 + c]) = v;
  }
}

// ---------------------------------------------------------------------------
// Flash attention v8 (R3/R5/R6-verified, 153 us) — restored after v10's
// regression (R10 counters: launch_bounds(512,4) -> 64-VGPR budget
// (VGPR=60, strangled), and cross-block work pairing failed temporally
// (light blocks die early -> occupancy 27% not 50%). v8's intra-block
// pairing {bx, 63-bx} keeps per-block work constant at 65 units.
// ---------------------------------------------------------------------------
__global__ __launch_bounds__(256, 2) void attn(const bf16* __restrict__ q,
                                               const bf16* __restrict__ k,
                                               const bf16* __restrict__ vt,
                                               bf16* __restrict__ out) {
  __shared__ __align__(16) bf16 Ks[2][64 * 128];  // [buf][kv row][dim] swizzled
  __shared__ __align__(16) bf16 Vs[2][128 * 64];  // [buf][dim][kv row] swizzled

  const int head = blockIdx.y, kvh = head >> 1;
  const int bx = blockIdx.x;

  const int tid = threadIdx.x;
  const int wave = tid >> 6, lane = tid & 63;
  const int quad = lane >> 4, l16 = lane & 15;
  const float cExp = 0.08838834764831845f * 1.4426950408889634f; // scale*log2e
  const f32x4 zero = {0.f, 0.f, 0.f, 0.f};

  int kSrc[4], vSrc[4];
#pragma unroll
  for (int it = 0; it < 4; ++it) {
    int r = (wave * 4 + it) * 4 + (lane >> 4);
    kSrc[it] = r * 1024 + kvh * 128 + (((lane & 15) ^ (r & 7)) << 3);
    int d = (wave * 4 + it) * 8 + (lane >> 3);
    vSrc[it] = (kvh * 128 + d) * 4096 + (((lane & 7) ^ (lane >> 3)) << 3);
  }

  const int kswz = (l16 & 7) << 3;
  int koff[4], voff[4];
#pragma unroll
  for (int s = 0; s < 4; ++s) {
    koff[s] = (s * 32 + quad * 8) ^ kswz;
    voff[s] = (s * 16 + quad * 4) ^ kswz;
  }

#pragma unroll
  for (int it = 0; it < 4; ++it) {
    gload_lds16(&k[kSrc[it]], &Ks[0][(wave * 4 + it) * 512]);
    gload_lds16(&vt[vSrc[it]], &Vs[0][(wave * 4 + it) * 512]);
  }
  int cur = 0;

#pragma unroll
  for (int phase = 0; phase < 2; ++phase) {
    const int qt = phase == 0 ? bx : 63 - bx;
    const int q0 = qt * 64;
    const int kend = q0 + 64;
    const int qrow = q0 + wave * 16 + l16;

    bf16x8 qf[4];
#pragma unroll
    for (int s = 0; s < 4; ++s)
      qf[s] = *reinterpret_cast<const bf16x8*>(
          &q[(size_t)qrow * 2048 + head * 128 + s * 32 + quad * 8]);

    f32x4 o_acc[8];
#pragma unroll
    for (int dt = 0; dt < 8; ++dt) o_acc[dt] = zero;
    float m_i = -3.0e38f, l_i = 0.f;

    for (int k0 = 0; k0 < kend; k0 += 64) {
      __syncthreads();

      int nk0 = -1;
      if (k0 + 64 < kend)     nk0 = k0 + 64;
      else if (phase == 0)    nk0 = 0;
      if (nk0 >= 0) {
#pragma unroll
        for (int it = 0; it < 4; ++it) {
          gload_lds16(&k[kSrc[it] + nk0 * 1024],
                      &Ks[cur ^ 1][(wave * 4 + it) * 512]);
          gload_lds16(&vt[vSrc[it] + nk0],
                      &Vs[cur ^ 1][(wave * 4 + it) * 512]);
        }
      }

      const bf16* KsL = Ks[cur];
      const bf16* VsL = Vs[cur];

      f32x4 s_acc[4];
      __builtin_amdgcn_s_setprio(1);
#pragma unroll
      for (int mt = 0; mt < 4; ++mt) {
        bf16x8 kf[4];
#pragma unroll
        for (int ks = 0; ks < 4; ++ks)
          kf[ks] = *reinterpret_cast<const bf16x8*>(
              &KsL[(mt * 16 + l16) * 128 + koff[ks]]);
        f32x4 sa = zero;
#pragma unroll
        for (int ks = 0; ks < 4; ++ks) sa = mfma16(kf[ks], qf[ks], sa);
        s_acc[mt] = sa;
      }
      __builtin_amdgcn_s_setprio(0);

      if (k0 == q0) {
        int tq = wave * 16 + l16;
#pragma unroll
        for (int mt = 0; mt < 4; ++mt)
#pragma unroll
          for (int r = 0; r < 4; ++r) {
            int tk = mt * 16 + quad * 4 + r;
            if (tk > tq) s_acc[mt][r] = -3.0e38f;
          }
      }

      {
        float mx = -3.0e38f;
#pragma unroll
        for (int mt = 0; mt < 4; ++mt)
#pragma unroll
          for (int r = 0; r < 4; ++r) mx = fmaxf(mx, s_acc[mt][r]);
        mx = fmaxf(mx, __shfl_xor(mx, 16));
        mx = fmaxf(mx, __shfl_xor(mx, 32));
        if (!__all((mx - m_i) * cExp <= 8.0f)) {
          float mn = fmaxf(m_i, mx);
          float al = exp2f((m_i - mn) * cExp);
          m_i = mn;
          l_i *= al;
#pragma unroll
          for (int dt = 0; dt < 8; ++dt)
#pragma unroll
            for (int r = 0; r < 4; ++r) o_acc[dt][r] *= al;
        }
        float nmc = -m_i * cExp;
        float rs = 0.f;
#pragma unroll
        for (int mt = 0; mt < 4; ++mt)
#pragma unroll
          for (int r = 0; r < 4; ++r) {
            float pe = exp2f(fmaf(s_acc[mt][r], cExp, nmc));
            s_acc[mt][r] = pe;
            rs += pe;
          }
        rs += __shfl_xor(rs, 16);
        rs += __shfl_xor(rs, 32);
        l_i += rs;
      }

      bf16x4 pb[4];
#pragma unroll
      for (int mt = 0; mt < 4; ++mt) {
        bf16x4 t;
#pragma unroll
        for (int r = 0; r < 4; ++r) t[r] = (bf16)s_acc[mt][r];
        pb[mt] = t;
      }

      __builtin_amdgcn_s_setprio(1);
#pragma unroll
      for (int dt = 0; dt < 8; ++dt) {
        const bf16* vrow = &VsL[(dt * 16 + l16) * 64];
        bf16x4 va0 = *reinterpret_cast<const bf16x4*>(&vrow[voff[0]]);
        bf16x4 va1 = *reinterpret_cast<const bf16x4*>(&vrow[voff[1]]);
        bf16x4 va2 = *reinterpret_cast<const bf16x4*>(&vrow[voff[2]]);
        bf16x4 va3 = *reinterpret_cast<const bf16x4*>(&vrow[voff[3]]);
        mfma16x16_chain4(va0, va1, va2, va3, pb[0], pb[1], pb[2], pb[3],
                         o_acc[dt]);
      }
      __builtin_amdgcn_s_setprio(0);
      cur ^= 1;
    }

    float rl = __builtin_amdgcn_rcpf(l_i);
#pragma unroll
    for (int dt = 0; dt < 8; ++dt) {
      bf16x4 ov;
#pragma unroll
      for (int r = 0; r < 4; ++r) ov[r] = (bf16)(o_acc[dt][r] * rl);
      *reinterpret_cast<bf16x4*>(
          &out[(size_t)qrow * 2048 + head * 128 + dt * 16 + quad * 4]) = ov;
    }
  }
}

// ---------------------------------------------------------------------------
extern "C" void kernel_launch(void* const* d_in, const int* in_sizes, int n_in,
                              void* d_out, int out_size, void* d_ws, size_t ws_size,
                              hipStream_t stream) {
  const float* hidden = (const float*)d_in[0];
  const float* qkv_w  = (const float*)d_in[1];
  const float* qnw    = (const float*)d_in[2];
  const float* knw    = (const float*)d_in[3];
  const float* o_w    = (const float*)d_in[4];
  const int*   pos    = (const int*)d_in[5];

  bf16* qkv = (bf16*)d_ws;                       // 4096*4096
  bf16* qn  = qkv + (size_t)4096 * 4096;         // 4096*2048
  bf16* kn  = qn  + (size_t)4096 * 2048;         // 4096*1024
  bf16* vt  = kn  + (size_t)4096 * 1024;         // 1024*4096
  bf16* ao  = vt  + (size_t)1024 * 4096;         // 4096*2048
  bf16* hb  = ao;   // bf16 hidden, dead before attn writes ao
  bf16* wq  = kn;   // bf16 qkv_w, dead before norm_rope/transpose write kn/vt
  bf16* wo  = qn;   // bf16 o_w, cast after attn (qn dead)
  float* out = (float*)d_out;

  cast_bf16<<<4096, 256, 0, stream>>>(hidden, hb);
  cast_bf16<<<4096, 256, 0, stream>>>(qkv_w, wq);
  gemm8ph<<<256, 512, 0, stream>>>(hb, wq, qkv, 4096, 4096, 2048);
  norm_rope<<<4096, 256, 0, stream>>>(qkv, qnw, knw, pos, qn, kn);
  transpose_v<<<dim3(64, 8), 256, 0, stream>>>(qkv, vt);
  attn<<<dim3(32, 16), 256, 0, stream>>>(qn, kn, vt, ao);
  cast_bf16<<<2048, 256, 0, stream>>>(o_w, wo);
  gemm8ph_n128<<<256, 512, 0, stream>>>(ao, wo, out, 4096, 2048, 2048);
}